// Round 4
// baseline (458.476 us; speedup 1.0000x reference)
//
#include <hip/hip_runtime.h>
#include <math.h>

// Problem constants (from reference)
#define N_SAMP 200000
#define D_     128
#define T_     8
#define P_     2000
#define NP_    9
#define H_     2048
#define MPAD   2048          // padded M for guard-free MFMA GEMM

// ---------------------------------------------------------------------------
// Workspace layout (bytes, 256-aligned). h2 overlays {fphi,fplo,w1thi,w1tlo}
// (dead after GEMM1). tsum/tcnt overlay h1hi (dead until GEMM1 writes it).
// ---------------------------------------------------------------------------
#define OFF_PTSUM   0
#define SZ_PTSUM    (16000*128*4)      // 8,192,000
#define OFF_PTCNT   8192000
#define SZ_PTCNT    (16000*4)
#define OFF_FIRST   8256000
#define SZ_FIRST    (P_*4)
#define OFF_TMEAN   8264192
#define OFF_FPHI    8268288            // 2048*1024*2 = 4,194,304
#define OFF_FPLO    12462592
#define OFF_W1THI   16656896
#define OFF_W1TLO   20851200
#define OFF_H1HI    25045504           // 2048*2048*2 = 8,388,608
#define OFF_H1LO    33434112
#define OFF_W2THI   41822720
#define OFF_W2TLO   50211328
#define OFF_H2      OFF_FPHI           // overlay (16,777,216 B exactly)
#define OFF_TSUM    OFF_H1HI           // overlay: 1024 f32 partial sums
#define OFF_TCNT    (OFF_H1HI + 4096)  // 8 f32 task counts

typedef __attribute__((ext_vector_type(8))) short bf16x8;
typedef __attribute__((ext_vector_type(4))) float f32x4;

// bf16 split helpers (bit ops, RNE)
__device__ __forceinline__ unsigned f2bf_rne(float x) {
    unsigned b = __float_as_uint(x);
    return (b + 0x7fffu + ((b >> 16) & 1u)) >> 16;
}
__device__ __forceinline__ float bf2f(unsigned u) {
    return __uint_as_float(u << 16);
}

// async global->LDS, 16B/lane: LDS dest = wave-uniform base + lane*16 [m97/m104]
__device__ __forceinline__ void gload16(const void* g, void* l) {
    __builtin_amdgcn_global_load_lds(
        (const __attribute__((address_space(1))) unsigned int*)g,
        (__attribute__((address_space(3))) unsigned int*)l, 16, 0, 0);
}

// ---------------------------------------------------------------------------
// Kernel 1: scatter-reduce, grid-stride waves (2048 blocks x 4 waves).
// ---------------------------------------------------------------------------
__global__ __launch_bounds__(256) void scatter_pt(
    const float* __restrict__ motion_z, const int* __restrict__ tasks,
    const int* __restrict__ tmask, const int* __restrict__ pids,
    const int* __restrict__ pmask, float* __restrict__ pt_sum,
    float* __restrict__ pt_cnt, int* __restrict__ first)
{
    int wid0 = (blockIdx.x * blockDim.x + threadIdx.x) >> 6;
    int lane = threadIdx.x & 63;
    int nw   = (gridDim.x * blockDim.x) >> 6;
    for (int wid = wid0; wid < N_SAMP; wid += nw) {
        if (tmask[wid] != 1 || pmask[wid] != 1) continue;
        int seg = pids[wid] * T_ + tasks[wid];
        if (lane == 0) {
            atomicAdd(&pt_cnt[seg], 1.0f);
            atomicMin(&first[pids[wid]], wid);
        }
        float2 v = *(const float2*)&motion_z[(size_t)wid * D_ + lane * 2];
        atomicAdd(&pt_sum[seg * D_ + lane * 2 + 0], v.x);
        atomicAdd(&pt_sum[seg * D_ + lane * 2 + 1], v.y);
    }
}

// ---------------------------------------------------------------------------
// Kernel 2a: streaming partial reduce over patients for task mean.
// ---------------------------------------------------------------------------
__global__ __launch_bounds__(256) void tsum_partial(
    const float* __restrict__ pt_sum, const float* __restrict__ pt_cnt,
    float* __restrict__ tsum, float* __restrict__ tcnt)
{
    int p0 = blockIdx.x * 16;
    int tid = threadIdx.x;
    float4 acc = make_float4(0.f, 0.f, 0.f, 0.f);
    for (int pl = 0; pl < 16; ++pl) {
        float4 v = *(const float4*)&pt_sum[(size_t)(p0 + pl) * 1024 + tid * 4];
        acc.x += v.x; acc.y += v.y; acc.z += v.z; acc.w += v.w;
    }
    atomicAdd(&tsum[tid * 4 + 0], acc.x);
    atomicAdd(&tsum[tid * 4 + 1], acc.y);
    atomicAdd(&tsum[tid * 4 + 2], acc.z);
    atomicAdd(&tsum[tid * 4 + 3], acc.w);
    if (tid < 128) {
        int p = p0 + (tid >> 3), t = tid & 7;
        atomicAdd(&tcnt[t], pt_cnt[p * 8 + t]);
    }
}

// Kernel 2b: tmean = tsum / max(tcnt,1)   (1024 elems)
__global__ __launch_bounds__(256) void tmean_div(
    const float* __restrict__ tsum, const float* __restrict__ tcnt,
    float* __restrict__ tmean)
{
    int e = blockIdx.x * 256 + threadIdx.x;
    if (e >= 1024) return;
    tmean[e] = tsum[e] / fmaxf(tcnt[e >> 7], 1.0f);
}

// ---------------------------------------------------------------------------
// Kernel 3: finalize fingerprint -> bf16 hi/lo, rows padded to 2048 (zeros).
// ---------------------------------------------------------------------------
__global__ __launch_bounds__(256) void finalize_split(
    const float* __restrict__ pt_sum, const float* __restrict__ pt_cnt,
    const float* __restrict__ tmean,
    unsigned short* __restrict__ fphi, unsigned short* __restrict__ fplo)
{
    int e = blockIdx.x * blockDim.x + threadIdx.x;   // over 2048*1024
    int p = e >> 10, col = e & 1023;
    float v = 0.f;
    if (p < P_) {
        int seg = p * T_ + (col >> 7);
        float c = pt_cnt[seg];
        v = (c > 0.f) ? pt_sum[e] / c : tmean[col];
    }
    unsigned hi = f2bf_rne(v);
    float lo = v - bf2f(hi);
    fphi[e] = (unsigned short)hi;
    fplo[e] = (unsigned short)f2bf_rne(lo);
}

// ---------------------------------------------------------------------------
// Kernel 4: gather first-valid pheno row per patient.
// ---------------------------------------------------------------------------
__global__ void gather_phenos(const int* __restrict__ first,
                              const float* __restrict__ phenos,
                              float* __restrict__ up)
{
    int e = blockIdx.x * blockDim.x + threadIdx.x;
    if (e >= P_ * NP_) return;
    int p = e / NP_, j = e - p * NP_;
    int idx = first[p];
    if (idx > N_SAMP - 1) idx = N_SAMP - 1;
    up[e] = phenos[(size_t)idx * NP_ + j];
}

// ---------------------------------------------------------------------------
// Kernel 5: W [K][N] f32 -> Wt hi/lo bf16 [N][K] (transpose + split).
// ---------------------------------------------------------------------------
__global__ __launch_bounds__(256) void conv_w_t(
    const float* __restrict__ W, unsigned short* __restrict__ Whi,
    unsigned short* __restrict__ Wlo, int K, int N)
{
    __shared__ float tile[32][36];
    int k0 = blockIdx.y * 32, n0 = blockIdx.x * 32;
    int r = threadIdx.x >> 3, c4 = (threadIdx.x & 7) * 4;
    float4 v = *(const float4*)&W[(size_t)(k0 + r) * N + n0 + c4];
    tile[r][c4 + 0] = v.x; tile[r][c4 + 1] = v.y;
    tile[r][c4 + 2] = v.z; tile[r][c4 + 3] = v.w;
    __syncthreads();
    unsigned short hi[4], lo[4];
#pragma unroll
    for (int q = 0; q < 4; ++q) {
        float x = tile[c4 + q][r];
        unsigned h = f2bf_rne(x);
        hi[q] = (unsigned short)h;
        lo[q] = (unsigned short)f2bf_rne(x - bf2f(h));
    }
    size_t o = (size_t)(n0 + r) * K + k0 + c4;
    *(ushort4*)&Whi[o] = make_ushort4(hi[0], hi[1], hi[2], hi[3]);
    *(ushort4*)&Wlo[o] = make_ushort4(lo[0], lo[1], lo[2], lo[3]);
}

// ---------------------------------------------------------------------------
// Kernel 6: MFMA split-precision GEMM, fragment-ordered LDS + global_load_lds.
// A: hi/lo bf16 [MPAD][K] row-major. B: hi/lo bf16 [N][K] (pre-transposed).
// 128x64 tile, 4 waves (64x32 each), double-buffered 48KB LDS
// -> grid 512 blocks = 2 independent blocks/CU (TLP hides the barrier drain).
// LDS layout: [buf][chunk 0..23][lane*16B]; chunks: 0-7 Ahi tiles, 8-15 Alo,
// 16-19 Bhi, 20-23 Blo. Every ds_read_b128 is a contiguous 1KB wave read
// (conflict-free, R2-verified: SQ_LDS_BANK_CONFLICT=0); every stage is one
// global_load_lds_dwordx4 (uniform LDS base + lane*16).
// ---------------------------------------------------------------------------
template<int OUTF32>
__global__ __launch_bounds__(256, 2) void gemm_split(
    const unsigned short* __restrict__ Ahi, const unsigned short* __restrict__ Alo,
    const unsigned short* __restrict__ Bhi, const unsigned short* __restrict__ Blo,
    const float* __restrict__ bias,
    float* __restrict__ Cf, unsigned short* __restrict__ Chi,
    unsigned short* __restrict__ Clo, int K)
{
    __shared__ __align__(16) char lds[2][24 * 1024];   // 48 KiB
    int tid  = threadIdx.x;
    int lane = tid & 63, w = tid >> 6;
    int wr = w >> 1, wc = w & 1;
    int row0 = blockIdx.y * 128, col0 = blockIdx.x * 64;

    // per-lane fragment source coordinates (lane l holds X[l&15][k0+(l>>4)*8..+7])
    int fr = lane & 15;
    int fk = (lane >> 4) * 8;

    auto STAGE = [&](int buf, int t) {
        int k0 = t * 32;
#pragma unroll
        for (int u = 0; u < 6; ++u) {
            int idx = u * 4 + w;                 // wave-uniform chunk id
            const unsigned short* src;
            int base, tile;
            if (idx < 8)       { src = Ahi; base = row0; tile = idx; }
            else if (idx < 16) { src = Alo; base = row0; tile = idx - 8; }
            else if (idx < 20) { src = Bhi; base = col0; tile = idx - 16; }
            else               { src = Blo; base = col0; tile = idx - 20; }
            gload16(src + (size_t)(base + tile * 16 + fr) * K + k0 + fk,
                    &lds[buf][idx * 1024]);
        }
    };

    f32x4 acc[4][2] = {};
    int nt = K / 32;
    STAGE(0, 0);
    __syncthreads();
    int cur = 0;
    int lo16 = lane * 16;

    for (int t = 0; t < nt; ++t) {
        if (t + 1 < nt) STAGE(cur ^ 1, t + 1);
        bf16x8 ah[4], al[4], bh[2], bl[2];
#pragma unroll
        for (int i = 0; i < 4; ++i) {
            ah[i] = *(const bf16x8*)&lds[cur][(wr * 4 + i) * 1024 + lo16];
            al[i] = *(const bf16x8*)&lds[cur][(8 + wr * 4 + i) * 1024 + lo16];
        }
#pragma unroll
        for (int j = 0; j < 2; ++j) {
            bh[j] = *(const bf16x8*)&lds[cur][(16 + wc * 2 + j) * 1024 + lo16];
            bl[j] = *(const bf16x8*)&lds[cur][(20 + wc * 2 + j) * 1024 + lo16];
        }
        __builtin_amdgcn_s_setprio(1);
#pragma unroll
        for (int i = 0; i < 4; ++i)
#pragma unroll
            for (int j = 0; j < 2; ++j) {
                acc[i][j] = __builtin_amdgcn_mfma_f32_16x16x32_bf16(ah[i], bh[j], acc[i][j], 0, 0, 0);
                acc[i][j] = __builtin_amdgcn_mfma_f32_16x16x32_bf16(ah[i], bl[j], acc[i][j], 0, 0, 0);
                acc[i][j] = __builtin_amdgcn_mfma_f32_16x16x32_bf16(al[i], bh[j], acc[i][j], 0, 0, 0);
            }
        __builtin_amdgcn_s_setprio(0);
        __syncthreads();     // drains staged loads + frees cur for next stage
        cur ^= 1;
    }

    // Epilogue: C/D layout col=lane&15, row=(lane>>4)*4+reg  [m89-verified]
#pragma unroll
    for (int i = 0; i < 4; ++i) {
        int r = row0 + wr * 64 + i * 16 + (lane >> 4) * 4;
#pragma unroll
        for (int j = 0; j < 2; ++j) {
            int c = col0 + wc * 32 + j * 16 + (lane & 15);
            float bv = bias[c];
#pragma unroll
            for (int q = 0; q < 4; ++q) {
                float x = fmaxf(acc[i][j][q] + bv, 0.f);
                size_t o = (size_t)(r + q) * H_ + c;
                if (OUTF32) {
                    Cf[o] = x;
                } else {
                    unsigned hb = f2bf_rne(x);
                    Chi[o] = (unsigned short)hb;
                    Clo[o] = (unsigned short)f2bf_rne(x - bf2f(hb));
                }
            }
        }
    }
}

// ---------------------------------------------------------------------------
// Kernel 7: head GEMM [2000,2048]@[2048,9] + b3 -> latent; out = sigmoid.
// ---------------------------------------------------------------------------
__global__ __launch_bounds__(256) void out_head(
    const float* __restrict__ h2, const float* __restrict__ W3,
    const float* __restrict__ b3, float* __restrict__ out,
    float* __restrict__ latent)
{
    int wid  = (blockIdx.x * blockDim.x + threadIdx.x) >> 6;
    int lane = threadIdx.x & 63;
    if (wid >= P_) return;
    const float* hrow = h2 + (size_t)wid * H_;
    float acc[NP_] = {};
    for (int k = lane; k < H_; k += 64) {
        float h = hrow[k];
        const float* wr = W3 + (size_t)k * NP_;
#pragma unroll
        for (int j = 0; j < NP_; ++j) acc[j] = fmaf(h, wr[j], acc[j]);
    }
#pragma unroll
    for (int off = 32; off > 0; off >>= 1)
#pragma unroll
        for (int j = 0; j < NP_; ++j) acc[j] += __shfl_down(acc[j], off);
    if (lane == 0) {
#pragma unroll
        for (int j = 0; j < NP_; ++j) {
            float v = acc[j] + b3[j];
            latent[wid * NP_ + j] = v;
            out[wid * NP_ + j]    = 1.f / (1.f + expf(-v));
        }
    }
}

// ---------------------------------------------------------------------------
extern "C" void kernel_launch(void* const* d_in, const int* in_sizes, int n_in,
                              void* d_out, int out_size, void* d_ws, size_t ws_size,
                              hipStream_t stream)
{
    const float* motion_z = (const float*)d_in[0];
    const int*   tasks    = (const int*)d_in[1];
    const int*   tmask    = (const int*)d_in[2];
    const int*   pids     = (const int*)d_in[3];
    const float* phenos   = (const float*)d_in[4];
    const int*   pmask    = (const int*)d_in[5];
    const float* W1 = (const float*)d_in[6];
    const float* b1 = (const float*)d_in[7];
    const float* W2 = (const float*)d_in[8];
    const float* b2 = (const float*)d_in[9];
    const float* W3 = (const float*)d_in[10];
    const float* b3 = (const float*)d_in[11];

    char* ws = (char*)d_ws;
    float*          pt_sum = (float*)(ws + OFF_PTSUM);
    float*          pt_cnt = (float*)(ws + OFF_PTCNT);
    int*            first  = (int*)  (ws + OFF_FIRST);
    float*          tmean  = (float*)(ws + OFF_TMEAN);
    float*          tsum   = (float*)(ws + OFF_TSUM);
    float*          tcnt   = (float*)(ws + OFF_TCNT);
    unsigned short* fphi   = (unsigned short*)(ws + OFF_FPHI);
    unsigned short* fplo   = (unsigned short*)(ws + OFF_FPLO);
    unsigned short* w1thi  = (unsigned short*)(ws + OFF_W1THI);
    unsigned short* w1tlo  = (unsigned short*)(ws + OFF_W1TLO);
    unsigned short* h1hi   = (unsigned short*)(ws + OFF_H1HI);
    unsigned short* h1lo   = (unsigned short*)(ws + OFF_H1LO);
    unsigned short* w2thi  = (unsigned short*)(ws + OFF_W2THI);
    unsigned short* w2tlo  = (unsigned short*)(ws + OFF_W2TLO);
    float*          h2     = (float*)(ws + OFF_H2);

    float* out    = (float*)d_out;
    float* uni    = out + P_ * NP_;
    float* latent = out + 2 * P_ * NP_;

    hipMemsetAsync(pt_sum, 0,    SZ_PTSUM, stream);
    hipMemsetAsync(pt_cnt, 0,    SZ_PTCNT, stream);
    hipMemsetAsync(first,  0x7f, SZ_FIRST, stream);
    hipMemsetAsync(tsum,   0,    4096 + 256, stream);   // tsum + tcnt

    scatter_pt<<<2048, 256, 0, stream>>>(motion_z, tasks, tmask, pids,
                                         pmask, pt_sum, pt_cnt, first);
    tsum_partial<<<125, 256, 0, stream>>>(pt_sum, pt_cnt, tsum, tcnt);
    tmean_div<<<4, 256, 0, stream>>>(tsum, tcnt, tmean);
    finalize_split<<<(MPAD * 1024) / 256, 256, 0, stream>>>(
        pt_sum, pt_cnt, tmean, fphi, fplo);
    gather_phenos<<<(P_ * NP_ + 255) / 256, 256, 0, stream>>>(first, phenos, uni);

    conv_w_t<<<dim3(H_ / 32, 1024 / 32), 256, 0, stream>>>(W1, w1thi, w1tlo, 1024, H_);
    conv_w_t<<<dim3(H_ / 32, H_ / 32),   256, 0, stream>>>(W2, w2thi, w2tlo, H_, H_);

    // GEMM1: fingerprint[2048,1024] @ W1 -> h1 (relu, bf16 hi/lo out)
    gemm_split<0><<<dim3(H_ / 64, MPAD / 128), 256, 0, stream>>>(
        fphi, fplo, w1thi, w1tlo, b1, nullptr, h1hi, h1lo, 1024);
    // GEMM2: h1[2048,2048] @ W2 -> h2 (relu, f32 out)
    gemm_split<1><<<dim3(H_ / 64, MPAD / 128), 256, 0, stream>>>(
        h1hi, h1lo, w2thi, w2tlo, b2, h2, nullptr, nullptr, H_);

    out_head<<<P_ / 4, 256, 0, stream>>>(h2, W3, b3, out, latent);
}

// Round 5
// 425.038 us; speedup vs baseline: 1.0787x; 1.0787x over previous
//
#include <hip/hip_runtime.h>
#include <math.h>

// Problem constants (from reference)
#define N_SAMP 200000
#define D_     128
#define T_     8
#define P_     2000
#define NP_    9
#define H_     2048
#define MPAD   2048          // padded M for guard-free MFMA GEMM
#define NSEG   16000
#define NSEGP  16384         // padded segment count for scan

// ---------------------------------------------------------------------------
// Workspace layout (bytes). h2 overlays {fphi,fplo,w1thi,w1tlo} (dead after
// GEMM1; exactly 16,777,216 B). Total ~59.5 MB.
// ---------------------------------------------------------------------------
#define OFF_CNT     0                  // 16384 int
#define OFF_CURSOR  65536              // 16384 int
#define OFF_OFFS    131072             // 16384 int
#define OFF_FIRST   196608             // 2000 int (pad 8192)
#define OFF_PERM    204800             // 200000 int
#define OFF_TMEAN   1004800            // 1024 f32
#define OFF_TSUM    1008896            // 1024 f32
#define OFF_TCNT    1012992            // 8 f32 (pad)
#define OFF_PTSUM   1013760            // 16000*128 f32 = 8,192,000
#define OFF_FPHI    9205760            // 2048*1024 bf16 = 4,194,304
#define OFF_FPLO    13400064
#define OFF_W1THI   17594368
#define OFF_W1TLO   21788672
#define OFF_H1HI    25982976           // 2048*2048 bf16 = 8,388,608
#define OFF_H1LO    34371584
#define OFF_W2THI   42760192
#define OFF_W2TLO   51148800
#define OFF_H2      OFF_FPHI           // overlay (16,777,216 B exactly)

typedef __attribute__((ext_vector_type(8))) short bf16x8;
typedef __attribute__((ext_vector_type(4))) float f32x4;

// bf16 split helpers (bit ops, RNE)
__device__ __forceinline__ unsigned f2bf_rne(float x) {
    unsigned b = __float_as_uint(x);
    return (b + 0x7fffu + ((b >> 16) & 1u)) >> 16;
}
__device__ __forceinline__ float bf2f(unsigned u) {
    return __uint_as_float(u << 16);
}

// async global->LDS, 16B/lane: LDS dest = wave-uniform base + lane*16 [m97/m104]
__device__ __forceinline__ void gload16(const void* g, void* l) {
    __builtin_amdgcn_global_load_lds(
        (const __attribute__((address_space(1))) unsigned int*)g,
        (__attribute__((address_space(3))) unsigned int*)l, 16, 0, 0);
}

// ---------------------------------------------------------------------------
// Kernel 1: histogram + first-valid-index. One thread per row.
// ~50k int atomics (vs 6.4M f32 atomics of the old scatter).
// ---------------------------------------------------------------------------
__global__ __launch_bounds__(256) void hist_first(
    const int* __restrict__ tasks, const int* __restrict__ tmask,
    const int* __restrict__ pids, const int* __restrict__ pmask,
    int* __restrict__ cnt, int* __restrict__ first)
{
    int i = blockIdx.x * 256 + threadIdx.x;
    if (i >= N_SAMP) return;
    if (tmask[i] != 1 || pmask[i] != 1) return;
    int p = pids[i];
    atomicAdd(&cnt[p * T_ + tasks[i]], 1);
    atomicMin(&first[p], i);
}

// ---------------------------------------------------------------------------
// Kernel 2: exclusive prefix scan of 16384 counts. Single block, 256 threads,
// 64 elements per thread + Hillis-Steele block scan.
// ---------------------------------------------------------------------------
__global__ __launch_bounds__(256) void scan16k(
    const int* __restrict__ cnt, int* __restrict__ offs)
{
    __shared__ int part[256];
    int tid = threadIdx.x;
    int base = tid * 64;
    int s = 0;
#pragma unroll 8
    for (int j = 0; j < 64; ++j) s += cnt[base + j];
    part[tid] = s;
    __syncthreads();
    for (int d = 1; d < 256; d <<= 1) {
        int v = (tid >= d) ? part[tid - d] : 0;
        __syncthreads();
        part[tid] += v;
        __syncthreads();
    }
    int run = (tid > 0) ? part[tid - 1] : 0;
    for (int j = 0; j < 64; ++j) {
        offs[base + j] = run;
        run += cnt[base + j];
    }
}

// ---------------------------------------------------------------------------
// Kernel 3: scatter row indices into per-segment contiguous lists.
// ---------------------------------------------------------------------------
__global__ __launch_bounds__(256) void scatter_idx(
    const int* __restrict__ tasks, const int* __restrict__ tmask,
    const int* __restrict__ pids, const int* __restrict__ pmask,
    const int* __restrict__ offs, int* __restrict__ cursor,
    int* __restrict__ perm)
{
    int i = blockIdx.x * 256 + threadIdx.x;
    if (i >= N_SAMP) return;
    if (tmask[i] != 1 || pmask[i] != 1) return;
    int seg = pids[i] * T_ + tasks[i];
    int pos = atomicAdd(&cursor[seg], 1);
    perm[offs[seg] + pos] = i;
}

// ---------------------------------------------------------------------------
// Kernel 4: gather-reduce. One wave per (patient,task) cell; sums its rows'
// motion_z (coalesced 512B row reads), writes cell SUM (zeros if empty).
// Replaces the atomic scatter AND the pt_sum memset.
// ---------------------------------------------------------------------------
__global__ __launch_bounds__(256) void gather_cell(
    const float* __restrict__ motion_z, const int* __restrict__ cnt,
    const int* __restrict__ offs, const int* __restrict__ perm,
    float* __restrict__ pt_sum)
{
    int wid  = (blockIdx.x * 256 + threadIdx.x) >> 6;
    int lane = threadIdx.x & 63;
    if (wid >= NSEG) return;
    int c = cnt[wid], base = offs[wid];
    float2 acc = make_float2(0.f, 0.f);
    for (int r = 0; r < c; ++r) {
        int idx = perm[base + r];
        float2 v = *(const float2*)&motion_z[(size_t)idx * D_ + lane * 2];
        acc.x += v.x; acc.y += v.y;
    }
    *(float2*)&pt_sum[(size_t)wid * D_ + lane * 2] = acc;
}

// ---------------------------------------------------------------------------
// Kernel 5: streaming partial reduce over patients for task mean.
// ---------------------------------------------------------------------------
__global__ __launch_bounds__(256) void tsum_partial(
    const float* __restrict__ pt_sum, const int* __restrict__ cnt,
    float* __restrict__ tsum, float* __restrict__ tcnt)
{
    int p0 = blockIdx.x * 16;
    int tid = threadIdx.x;
    float4 acc = make_float4(0.f, 0.f, 0.f, 0.f);
    for (int pl = 0; pl < 16; ++pl) {
        float4 v = *(const float4*)&pt_sum[(size_t)(p0 + pl) * 1024 + tid * 4];
        acc.x += v.x; acc.y += v.y; acc.z += v.z; acc.w += v.w;
    }
    atomicAdd(&tsum[tid * 4 + 0], acc.x);
    atomicAdd(&tsum[tid * 4 + 1], acc.y);
    atomicAdd(&tsum[tid * 4 + 2], acc.z);
    atomicAdd(&tsum[tid * 4 + 3], acc.w);
    if (tid < 128) {
        int p = p0 + (tid >> 3), t = tid & 7;
        atomicAdd(&tcnt[t], (float)cnt[p * 8 + t]);
    }
}

// ---------------------------------------------------------------------------
// Kernel 6: fused tmean divide (1024 elems) + pheno gather (18000 elems).
// ---------------------------------------------------------------------------
__global__ __launch_bounds__(256) void tmean_gather(
    const float* __restrict__ tsum, const float* __restrict__ tcnt,
    float* __restrict__ tmean, const int* __restrict__ first,
    const float* __restrict__ phenos, float* __restrict__ up)
{
    int e = blockIdx.x * 256 + threadIdx.x;
    if (e < 1024) {
        tmean[e] = tsum[e] / fmaxf(tcnt[e >> 7], 1.0f);
    } else {
        int g = e - 1024;
        if (g < P_ * NP_) {
            int p = g / NP_, j = g - p * NP_;
            int idx = first[p];
            if (idx > N_SAMP - 1) idx = N_SAMP - 1;
            up[g] = phenos[(size_t)idx * NP_ + j];
        }
    }
}

// ---------------------------------------------------------------------------
// Kernel 7: finalize fingerprint -> bf16 hi/lo, rows padded to 2048 (zeros).
// ---------------------------------------------------------------------------
__global__ __launch_bounds__(256) void finalize_split(
    const float* __restrict__ pt_sum, const int* __restrict__ cnt,
    const float* __restrict__ tmean,
    unsigned short* __restrict__ fphi, unsigned short* __restrict__ fplo)
{
    int e = blockIdx.x * blockDim.x + threadIdx.x;   // over 2048*1024
    int p = e >> 10, col = e & 1023;
    float v = 0.f;
    if (p < P_) {
        int seg = p * T_ + (col >> 7);
        int c = cnt[seg];
        v = (c > 0) ? pt_sum[e] / (float)c : tmean[col];
    }
    unsigned hi = f2bf_rne(v);
    float lo = v - bf2f(hi);
    fphi[e] = (unsigned short)hi;
    fplo[e] = (unsigned short)f2bf_rne(lo);
}

// ---------------------------------------------------------------------------
// Kernel 8: W [K][N] f32 -> Wt hi/lo bf16 [N][K] (transpose + split).
// tile[32][33]: read-side banks near-perfect (4a+b mod 32 distinct-ish).
// ---------------------------------------------------------------------------
__global__ __launch_bounds__(256) void conv_w_t(
    const float* __restrict__ W, unsigned short* __restrict__ Whi,
    unsigned short* __restrict__ Wlo, int K, int N)
{
    __shared__ float tile[32][33];
    int k0 = blockIdx.y * 32, n0 = blockIdx.x * 32;
    int r = threadIdx.x >> 3, c4 = (threadIdx.x & 7) * 4;
    float4 v = *(const float4*)&W[(size_t)(k0 + r) * N + n0 + c4];
    tile[r][c4 + 0] = v.x; tile[r][c4 + 1] = v.y;
    tile[r][c4 + 2] = v.z; tile[r][c4 + 3] = v.w;
    __syncthreads();
    unsigned short hi[4], lo[4];
#pragma unroll
    for (int q = 0; q < 4; ++q) {
        float x = tile[c4 + q][r];
        unsigned h = f2bf_rne(x);
        hi[q] = (unsigned short)h;
        lo[q] = (unsigned short)f2bf_rne(x - bf2f(h));
    }
    size_t o = (size_t)(n0 + r) * K + k0 + c4;
    *(ushort4*)&Whi[o] = make_ushort4(hi[0], hi[1], hi[2], hi[3]);
    *(ushort4*)&Wlo[o] = make_ushort4(lo[0], lo[1], lo[2], lo[3]);
}

// ---------------------------------------------------------------------------
// Kernel 9: MFMA split-precision GEMM (R3-measured config: 94 us @ K=2048).
// 128x128 tile, 4 waves (64x64), double-buffered 64KB fragment-ordered LDS,
// global_load_lds staging. SQ_LDS_BANK_CONFLICT = 0 (R3-verified).
// ---------------------------------------------------------------------------
template<int OUTF32>
__global__ __launch_bounds__(256, 1) void gemm_split(
    const unsigned short* __restrict__ Ahi, const unsigned short* __restrict__ Alo,
    const unsigned short* __restrict__ Bhi, const unsigned short* __restrict__ Blo,
    const float* __restrict__ bias,
    float* __restrict__ Cf, unsigned short* __restrict__ Chi,
    unsigned short* __restrict__ Clo, int K)
{
    __shared__ __align__(16) char lds[2][4][8192];   // 64 KiB
    int tid  = threadIdx.x;
    int lane = tid & 63, w = tid >> 6;
    int wr = w >> 1, wc = w & 1;
    int row0 = blockIdx.y * 128, col0 = blockIdx.x * 128;

    // per-lane fragment source coordinates (lane l holds X[l&15][k0+(l>>4)*8..+7])
    int fr = lane & 15;
    int fk = (lane >> 4) * 8;

    const unsigned short* srcs[4] = {Ahi, Alo, Bhi, Blo};
    int base0[4] = {row0, row0, col0, col0};

    auto STAGE = [&](int buf, int t) {
        int k0 = t * 32;
#pragma unroll
        for (int pc = 0; pc < 4; ++pc) {
#pragma unroll
            for (int rep = 0; rep < 2; ++rep) {
                int tile = rep * 4 + w;                       // wave-uniform
                const unsigned short* g =
                    srcs[pc] + (size_t)(base0[pc] + tile * 16 + fr) * K + k0 + fk;
                gload16(g, &lds[buf][pc][tile * 1024]);       // uniform base
            }
        }
    };

    f32x4 acc[4][4] = {};
    int nt = K / 32;
    STAGE(0, 0);
    __syncthreads();
    int cur = 0;
    int lo16 = lane * 16;

    for (int t = 0; t < nt; ++t) {
        if (t + 1 < nt) STAGE(cur ^ 1, t + 1);
        bf16x8 ah[4], al[4], bh[4], bl[4];
#pragma unroll
        for (int i = 0; i < 4; ++i) {
            ah[i] = *(const bf16x8*)&lds[cur][0][(wr * 4 + i) * 1024 + lo16];
            al[i] = *(const bf16x8*)&lds[cur][1][(wr * 4 + i) * 1024 + lo16];
        }
#pragma unroll
        for (int j = 0; j < 4; ++j) {
            bh[j] = *(const bf16x8*)&lds[cur][2][(wc * 4 + j) * 1024 + lo16];
            bl[j] = *(const bf16x8*)&lds[cur][3][(wc * 4 + j) * 1024 + lo16];
        }
#pragma unroll
        for (int i = 0; i < 4; ++i)
#pragma unroll
            for (int j = 0; j < 4; ++j) {
                acc[i][j] = __builtin_amdgcn_mfma_f32_16x16x32_bf16(ah[i], bh[j], acc[i][j], 0, 0, 0);
                acc[i][j] = __builtin_amdgcn_mfma_f32_16x16x32_bf16(ah[i], bl[j], acc[i][j], 0, 0, 0);
                acc[i][j] = __builtin_amdgcn_mfma_f32_16x16x32_bf16(al[i], bh[j], acc[i][j], 0, 0, 0);
            }
        __syncthreads();     // drains staged loads + frees cur for next stage
        cur ^= 1;
    }

    // Epilogue: C/D layout col=lane&15, row=(lane>>4)*4+reg  [m89-verified]
#pragma unroll
    for (int i = 0; i < 4; ++i) {
        int r = row0 + wr * 64 + i * 16 + (lane >> 4) * 4;
#pragma unroll
        for (int j = 0; j < 4; ++j) {
            int c = col0 + wc * 64 + j * 16 + (lane & 15);
            float bv = bias[c];
#pragma unroll
            for (int q = 0; q < 4; ++q) {
                float x = fmaxf(acc[i][j][q] + bv, 0.f);
                size_t o = (size_t)(r + q) * H_ + c;
                if (OUTF32) {
                    Cf[o] = x;
                } else {
                    unsigned hb = f2bf_rne(x);
                    Chi[o] = (unsigned short)hb;
                    Clo[o] = (unsigned short)f2bf_rne(x - bf2f(hb));
                }
            }
        }
    }
}

// ---------------------------------------------------------------------------
// Kernel 10: head GEMM + sigmoid, W3 staged in LDS (kills per-lane gather).
// LDS bank = (9k+j) mod 32, 9 coprime 32 -> 2-way (free).
// ---------------------------------------------------------------------------
__global__ __launch_bounds__(256) void out_head(
    const float* __restrict__ h2, const float* __restrict__ W3,
    const float* __restrict__ b3, float* __restrict__ out,
    float* __restrict__ latent)
{
    __shared__ float w3s[H_ * NP_];            // 73,728 B
    int tid = threadIdx.x;
    for (int e = tid * 4; e < H_ * NP_; e += 1024)
        *(float4*)&w3s[e] = *(const float4*)&W3[e];
    __syncthreads();

    int wid  = blockIdx.x * 4 + (tid >> 6);
    int lane = tid & 63;
    if (wid >= P_) return;
    const float* hrow = h2 + (size_t)wid * H_;
    float acc[NP_] = {};
    for (int k = lane; k < H_; k += 64) {
        float h = hrow[k];
#pragma unroll
        for (int j = 0; j < NP_; ++j) acc[j] = fmaf(h, w3s[k * NP_ + j], acc[j]);
    }
#pragma unroll
    for (int off = 32; off > 0; off >>= 1)
#pragma unroll
        for (int j = 0; j < NP_; ++j) acc[j] += __shfl_down(acc[j], off);
    if (lane == 0) {
#pragma unroll
        for (int j = 0; j < NP_; ++j) {
            float v = acc[j] + b3[j];
            latent[wid * NP_ + j] = v;
            out[wid * NP_ + j]    = 1.f / (1.f + expf(-v));
        }
    }
}

// ---------------------------------------------------------------------------
extern "C" void kernel_launch(void* const* d_in, const int* in_sizes, int n_in,
                              void* d_out, int out_size, void* d_ws, size_t ws_size,
                              hipStream_t stream)
{
    const float* motion_z = (const float*)d_in[0];
    const int*   tasks    = (const int*)d_in[1];
    const int*   tmask    = (const int*)d_in[2];
    const int*   pids     = (const int*)d_in[3];
    const float* phenos   = (const float*)d_in[4];
    const int*   pmask    = (const int*)d_in[5];
    const float* W1 = (const float*)d_in[6];
    const float* b1 = (const float*)d_in[7];
    const float* W2 = (const float*)d_in[8];
    const float* b2 = (const float*)d_in[9];
    const float* W3 = (const float*)d_in[10];
    const float* b3 = (const float*)d_in[11];

    char* ws = (char*)d_ws;
    int*            cnt    = (int*)  (ws + OFF_CNT);
    int*            cursor = (int*)  (ws + OFF_CURSOR);
    int*            offs   = (int*)  (ws + OFF_OFFS);
    int*            first  = (int*)  (ws + OFF_FIRST);
    int*            perm   = (int*)  (ws + OFF_PERM);
    float*          tmean  = (float*)(ws + OFF_TMEAN);
    float*          tsum   = (float*)(ws + OFF_TSUM);
    float*          tcnt   = (float*)(ws + OFF_TCNT);
    float*          pt_sum = (float*)(ws + OFF_PTSUM);
    unsigned short* fphi   = (unsigned short*)(ws + OFF_FPHI);
    unsigned short* fplo   = (unsigned short*)(ws + OFF_FPLO);
    unsigned short* w1thi  = (unsigned short*)(ws + OFF_W1THI);
    unsigned short* w1tlo  = (unsigned short*)(ws + OFF_W1TLO);
    unsigned short* h1hi   = (unsigned short*)(ws + OFF_H1HI);
    unsigned short* h1lo   = (unsigned short*)(ws + OFF_H1LO);
    unsigned short* w2thi  = (unsigned short*)(ws + OFF_W2THI);
    unsigned short* w2tlo  = (unsigned short*)(ws + OFF_W2TLO);
    float*          h2     = (float*)(ws + OFF_H2);

    float* out    = (float*)d_out;
    float* uni    = out + P_ * NP_;
    float* latent = out + 2 * P_ * NP_;

    hipMemsetAsync(cnt,   0,    2 * NSEGP * 4, stream);       // cnt + cursor
    hipMemsetAsync(first, 0x7f, P_ * 4, stream);
    hipMemsetAsync(tsum,  0,    4096 + 256, stream);          // tsum + tcnt

    int nrb = (N_SAMP + 255) / 256;
    hist_first<<<nrb, 256, 0, stream>>>(tasks, tmask, pids, pmask, cnt, first);
    scan16k<<<1, 256, 0, stream>>>(cnt, offs);
    scatter_idx<<<nrb, 256, 0, stream>>>(tasks, tmask, pids, pmask, offs,
                                         cursor, perm);
    gather_cell<<<(NSEG * 64 + 255) / 256, 256, 0, stream>>>(
        motion_z, cnt, offs, perm, pt_sum);
    tsum_partial<<<125, 256, 0, stream>>>(pt_sum, cnt, tsum, tcnt);
    tmean_gather<<<(1024 + P_ * NP_ + 255) / 256, 256, 0, stream>>>(
        tsum, tcnt, tmean, first, phenos, uni);
    finalize_split<<<(MPAD * 1024) / 256, 256, 0, stream>>>(
        pt_sum, cnt, tmean, fphi, fplo);

    conv_w_t<<<dim3(H_ / 32, 1024 / 32), 256, 0, stream>>>(W1, w1thi, w1tlo, 1024, H_);
    conv_w_t<<<dim3(H_ / 32, H_ / 32),   256, 0, stream>>>(W2, w2thi, w2tlo, H_, H_);

    // GEMM1: fingerprint[2048,1024] @ W1 -> h1 (relu, bf16 hi/lo out)
    gemm_split<0><<<dim3(H_ / 128, MPAD / 128), 256, 0, stream>>>(
        fphi, fplo, w1thi, w1tlo, b1, nullptr, h1hi, h1lo, 1024);
    // GEMM2: h1[2048,2048] @ W2 -> h2 (relu, f32 out)
    gemm_split<1><<<dim3(H_ / 128, MPAD / 128), 256, 0, stream>>>(
        h1hi, h1lo, w2thi, w2tlo, b2, h2, nullptr, nullptr, H_);

    out_head<<<P_ / 4, 256, 0, stream>>>(h2, W3, b3, out, latent);
}